// Round 12
// baseline (1153.141 us; speedup 1.0000x reference)
//
#include <hip/hip_runtime.h>

#define NN 200000
#define NB 64
#define NWG (NN / NB)   // 3125

typedef unsigned short u16;
typedef unsigned int u32;
typedef __attribute__((ext_vector_type(8))) short short8;
typedef __attribute__((ext_vector_type(4))) float f32x4;

#define LOG2E 1.4426950408889634f
#define TWOLOG2E 2.8853900817779268f

__device__ __forceinline__ u16 f2bf(float x) {
  u32 u = __float_as_uint(x);
  u += 0x7FFFu + ((u >> 16) & 1u);
  return (u16)(u >> 16);
}

// async global->LDS, 16B per lane; LDS dest = wave-uniform base + lane*16
typedef __attribute__((address_space(3))) unsigned int lds_u32_t;
typedef const __attribute__((address_space(1))) unsigned int glb_u32_t;
__device__ __forceinline__ void gload16(const void* g, void* l) {
  __builtin_amdgcn_global_load_lds((glb_u32_t*)g, (lds_u32_t*)l, 16, 0, 0);
}

// spin until LDS counter reaches 8 (all waves); compiler fence on exit
__device__ __forceinline__ void spin8(const volatile int* p) {
  while (*p < 8) { }
  asm volatile("" ::: "memory");
}

// msg[n][k] = bf16(feat[n][k] / out_norm[n]); 16 threads per row, 8 elems each
__global__ void k_prep_msg(const float* __restrict__ feat, const float* __restrict__ onorm,
                           u16* __restrict__ msg) {
  int i = blockIdx.x * 256 + threadIdx.x;   // 3,200,000 total, exact
  int row = i >> 4, c8 = (i & 15) * 8;
  const float4 a = *(const float4*)(feat + (size_t)row * 128 + c8);
  const float4 b = *(const float4*)(feat + (size_t)row * 128 + c8 + 4);
  float s = 1.0f / onorm[row];
  short8 v = { (short)f2bf(a.x * s), (short)f2bf(a.y * s), (short)f2bf(a.z * s), (short)f2bf(a.w * s),
               (short)f2bf(b.x * s), (short)f2bf(b.y * s), (short)f2bf(b.z * s), (short)f2bf(b.w * s) };
  *(short8*)(msg + (size_t)row * 128 + c8) = v;
}

// Weights with the gate nonlinearity scale FOLDED IN:
//  gates i,f,o: x * -log2(e)  (sigmoid via exp2);  gate g: x * 2*log2(e)
__global__ void k_prep_w(const float* __restrict__ Wih, const float* __restrict__ Whh,
                         const float* __restrict__ Wlin, const float* __restrict__ bih,
                         const float* __restrict__ bhh, u16* __restrict__ wihb,
                         u16* __restrict__ whhb, u16* __restrict__ wlinb,
                         float* __restrict__ bsum) {
  int i = blockIdx.x * 256 + threadIdx.x;   // 147,968 total, exact
  if (i < 65536) {
    int gate = i >> 14;
    float s = (gate == 2) ? TWOLOG2E : -LOG2E;
    wihb[i] = f2bf(Wih[i] * s);
  } else if (i < 131072) {
    int j = i - 65536;
    int gate = j >> 14;
    float s = (gate == 2) ? TWOLOG2E : -LOG2E;
    whhb[j] = f2bf(Whh[j] * s);
  } else if (i < 147456) {
    wlinb[i - 131072] = f2bf(Wlin[i - 131072]);
  } else {
    int j = i - 147456;   // 0..511
    float s = ((j >> 7) == 2) ? TWOLOG2E : -LOG2E;
    bsum[j] = (bih[j] + bhh[j]) * s;
  }
}

__global__ void k_hist(const int* __restrict__ degs, int* __restrict__ hist, int n) {
  __shared__ int lh[33];
  if (threadIdx.x < 33) lh[threadIdx.x] = 0;
  __syncthreads();
  int i = blockIdx.x * 256 + threadIdx.x;
  if (i < n) atomicAdd(&lh[degs[i]], 1);
  __syncthreads();
  if (threadIdx.x < 33 && lh[threadIdx.x]) atomicAdd(&hist[threadIdx.x], lh[threadIdx.x]);
}

__global__ void k_scan(const int* __restrict__ hist, int* __restrict__ basep) {
  if (threadIdx.x == 0 && blockIdx.x == 0) {
    int a = 0;
    for (int d = 32; d >= 1; --d) { basep[d] = a; a += hist[d]; }
    basep[0] = a;
  }
}

__global__ void k_scatter(const int* __restrict__ degs, int* __restrict__ basep,
                          int* __restrict__ perm, int n) {
  __shared__ int lh[33], lbase[33], lc[33];
  int t = threadIdx.x;
  if (t < 33) { lh[t] = 0; lc[t] = 0; }
  __syncthreads();
  int i = blockIdx.x * 256 + t;
  int d = (i < n) ? degs[i] : 0;
  if (i < n) atomicAdd(&lh[d], 1);
  __syncthreads();
  if (t < 33 && lh[t]) lbase[t] = atomicAdd(&basep[t], lh[t]);
  __syncthreads();
  if (i < n) { int r = atomicAdd(&lc[d], 1); perm[lbase[d] + r] = i; }
}

// Two INDEPENDENT 32-node recurrences (A rows 0-31, B rows 32-63) per block,
// each with its own flag set (R11's proven protocol). pub hr_A(t+1) sits a
// full B-phase (~half the body) before any consumer's spin hr_A(t+1), so
// chain-A latency hides under chain-B compute and vice versa — unlike R10,
// where the block-wide s_barrier re-serialized both. Register envelope and
// arithmetic identical to R11 (no-spill proven).
__global__ __launch_bounds__(512, 2) void k_main(
    const u16* __restrict__ msg, const u16* __restrict__ wihb,
    const u16* __restrict__ whhb, const u16* __restrict__ wlinb,
    const float* __restrict__ bsum, const float* __restrict__ blin,
    const float* __restrict__ inorm, const int* __restrict__ nbrs,
    const int* __restrict__ degs, const int* __restrict__ perm,
    float* __restrict__ out) {
  __shared__ alignas(16) u16 XA[3][32 * 128];   // X ring A (DMA dest, swizzled src)
  __shared__ alignas(16) u16 XB[3][32 * 128];   // X ring B
  __shared__ alignas(16) u16 Hb[2][64 * 136];   // h dbuf; A rows 0-31, B rows 32-63
  __shared__ int gidl[64];
  __shared__ int fl[144];   // hrA[0..33]=fl+0, hrB=fl+36, xrA=fl+72, xrB=fl+108
  // total ~84.5 KB

  const int tid = threadIdx.x;
  const int w = tid >> 6;
  const int lane = tid & 63;
  const int l15 = lane & 15;
  const int g4 = lane >> 4;
  const int w16 = w * 16;
  const int gr = tid >> 4;                        // gather row 0..31 (per recurrence)
  const int xc8 = (((tid & 15) ^ (gr & 15)) * 8); // swizzled source chunk (u16)
  const int wbase = w * 512;                      // wave's DMA dest base (u16)
  const int base = blockIdx.x * NB;
  volatile int* hrA = fl;         // hrA[t]==8 <=> h_A(t-1) published by all waves
  volatile int* hrB = fl + 36;
  volatile int* xrA = fl + 72;    // xrA[t]==8 <=> X_A(t) fully staged
  volatile int* xrB = fl + 108;

  // ---- phase 1: gidl, flags, zero Hb[1] (h(-1) for both recurrences) ----
  if (tid < NB) gidl[tid] = perm[base + tid];
  if (tid < 144) fl[tid] = 0;
  if (tid == 0) { fl[0] = 8; fl[36] = 8; }   // hrA[0], hrB[0] preset
  {
    u32* hz = (u32*)Hb[1];
#pragma unroll
    for (int s = 0; s < 8; ++s) hz[tid + s * 512] = 0;
    if (tid < 256) hz[tid + 4096] = 0;
  }
  __syncthreads();

  // ---- phase 2: per-wave loads + stage X_A(0..1), X_B(0..1) ----
  const int gidA = gidl[gr], gidB = gidl[32 + gr];
  const int* nbA = nbrs + (size_t)gidA * 32;
  const int* nbB = nbrs + (size_t)gidB * 32;

  gload16(msg + (size_t)nbA[0] * 128 + xc8, &XA[0][wbase]);
  gload16(msg + (size_t)nbB[0] * 128 + xc8, &XB[0][wbase]);
  gload16(msg + (size_t)nbA[1] * 128 + xc8, &XA[1][wbase]);   // row 1 always readable;
  gload16(msg + (size_t)nbB[1] * 128 + xc8, &XB[1][wbase]);   // unused if deg<2
  int niA = nbA[2], niB = nbB[2];   // indices for the DMAs at t=0 (stage X(2))

  short8 fih[4][4], fhh[4][4];
#pragma unroll
  for (int g = 0; g < 4; ++g)
#pragma unroll
    for (int kk = 0; kk < 4; ++kk) {
      size_t o = (size_t)(g * 128 + w16 + l15) * 128 + kk * 32 + g4 * 8;
      fih[g][kk] = *(const short8*)(wihb + o);
      fhh[g][kk] = *(const short8*)(whhb + o);
    }
  float bias[4];
#pragma unroll
  for (int g = 0; g < 4; ++g) bias[g] = bsum[g * 128 + w16 + l15];

  u32 dgp[4];
#pragma unroll
  for (int r = 0; r < 4; ++r) {
    u32 p = 0;
#pragma unroll
    for (int q = 0; q < 4; ++q) p |= ((u32)degs[gidl[r * 16 + g4 * 4 + q]]) << (8 * q);
    dgp[r] = p;
  }
  const int maxdegA = degs[gidl[0]];    // sorted descending (wave-uniform)
  const int maxdegB = degs[gidl[32]];   // <= maxdegA

  int xsw[4];
#pragma unroll
  for (int kk = 0; kk < 4; ++kk) xsw[kk] = ((kk * 4 + g4) ^ l15) * 8;

  float c[4][4] = {};     // A: rr 0-1, B: rr 2-3
  u32 hpk[4][2] = {};

  asm volatile("s_waitcnt vmcnt(0)" ::: "memory");
  if (lane == 0) {
    atomicAdd((int*)&xrA[0], 1); atomicAdd((int*)&xrA[1], 1);
    atomicAdd((int*)&xrB[0], 1); atomicAdd((int*)&xrB[1], 1);
  }

  for (int t = 0; t < maxdegA; ++t) {
    const int sl = t % 3, s2 = (t + 2) % 3;
    const u16* Hc = &Hb[(t + 1) & 1][0];   // h(t-1)
    u16* Hn = &Hb[t & 1][0];               // h(t) target

    // ================= recurrence A (rows 0-31) =================
    {
      spin8(&xrA[t]);
      f32x4 acc[2][4];
#pragma unroll
      for (int r = 0; r < 2; ++r)
#pragma unroll
        for (int g = 0; g < 4; ++g) acc[r][g] = (f32x4){bias[g], bias[g], bias[g], bias[g]};
      __builtin_amdgcn_s_setprio(1);
#pragma unroll
      for (int rf = 0; rf < 2; ++rf) {
        short8 ax[4];
#pragma unroll
        for (int kk = 0; kk < 4; ++kk)
          ax[kk] = *(const short8*)(&XA[sl][(rf * 16 + l15) * 128 + xsw[kk]]);
#pragma unroll
        for (int kk = 0; kk < 4; ++kk)
#pragma unroll
          for (int g = 0; g < 4; ++g)
            acc[rf][g] = __builtin_amdgcn_mfma_f32_16x16x32_bf16(ax[kk], fih[g][kk], acc[rf][g], 0, 0, 0);
      }
      __builtin_amdgcn_s_setprio(0);

      spin8(&hrA[t]);   // true cross-wave dep; expected pre-satisfied
      // ring slot s2 free: hrA[t]==8 => all waves' X-reads of step t-1 done
      if (t + 2 < maxdegA) gload16(msg + (size_t)niA * 128 + xc8, &XA[s2][wbase]);
      { int nt = (t + 3) <= 31 ? (t + 3) : 31; niA = nbA[nt]; }

      __builtin_amdgcn_s_setprio(1);
#pragma unroll
      for (int rf = 0; rf < 2; ++rf) {
        short8 ah[4];
#pragma unroll
        for (int kk = 0; kk < 4; ++kk)
          ah[kk] = *(const short8*)(&Hc[(rf * 16 + l15) * 136 + kk * 32 + g4 * 8]);
#pragma unroll
        for (int kk = 0; kk < 4; ++kk)
#pragma unroll
          for (int g = 0; g < 4; ++g)
            acc[rf][g] = __builtin_amdgcn_mfma_f32_16x16x32_bf16(ah[kk], fhh[g][kk], acc[rf][g], 0, 0, 0);
      }
      __builtin_amdgcn_s_setprio(0);
#pragma unroll
      for (int r = 0; r < 2; ++r)
#pragma unroll
        for (int q = 0; q < 4; ++q) {
          float ei = __builtin_amdgcn_exp2f(acc[r][0][q]);
          float ef = __builtin_amdgcn_exp2f(acc[r][1][q]);
          float eg = __builtin_amdgcn_exp2f(acc[r][2][q]);
          float eo = __builtin_amdgcn_exp2f(acc[r][3][q]);
          float fv  = __builtin_amdgcn_rcpf(1.0f + ef);
          float rig = __builtin_amdgcn_rcpf((1.0f + ei) * (1.0f + eg));
          float ig  = (eg - 1.0f) * rig;
          float cn  = fv * c[r][q] + ig;
          float ec  = __builtin_amdgcn_exp2f(cn * TWOLOG2E);
          float rho = __builtin_amdgcn_rcpf((1.0f + eo) * (1.0f + ec));
          float hn  = (ec - 1.0f) * rho;
          bool act = (int)((dgp[r] >> (8 * q)) & 255u) > t;
          c[r][q] = act ? cn : c[r][q];
          u32 word = hpk[r][q >> 1];
          u16 oldv = (u16)(word >> ((q & 1) * 16));
          u16 nh = act ? f2bf(hn) : oldv;
          hpk[r][q >> 1] = (q & 1) ? ((word & 0x0000FFFFu) | ((u32)nh << 16))
                                   : ((word & 0xFFFF0000u) | (u32)nh);
          Hn[(r * 16 + g4 * 4 + q) * 136 + w16 + l15] = nh;
        }
      asm volatile("s_waitcnt lgkmcnt(0)" ::: "memory");
      if (lane == 0) atomicAdd((int*)&hrA[t + 1], 1);
    }

    // ================= recurrence B (rows 32-63) =================
    if (t < maxdegB) {
      spin8(&xrB[t]);
      f32x4 acc[2][4];
#pragma unroll
      for (int r = 0; r < 2; ++r)
#pragma unroll
        for (int g = 0; g < 4; ++g) acc[r][g] = (f32x4){bias[g], bias[g], bias[g], bias[g]};
      __builtin_amdgcn_s_setprio(1);
#pragma unroll
      for (int rf = 0; rf < 2; ++rf) {
        short8 ax[4];
#pragma unroll
        for (int kk = 0; kk < 4; ++kk)
          ax[kk] = *(const short8*)(&XB[sl][(rf * 16 + l15) * 128 + xsw[kk]]);
#pragma unroll
        for (int kk = 0; kk < 4; ++kk)
#pragma unroll
          for (int g = 0; g < 4; ++g)
            acc[rf][g] = __builtin_amdgcn_mfma_f32_16x16x32_bf16(ax[kk], fih[g][kk], acc[rf][g], 0, 0, 0);
      }
      __builtin_amdgcn_s_setprio(0);

      spin8(&hrB[t]);
      if (t + 2 < maxdegB) gload16(msg + (size_t)niB * 128 + xc8, &XB[s2][wbase]);
      { int nt = (t + 3) <= 31 ? (t + 3) : 31; niB = nbB[nt]; }

      __builtin_amdgcn_s_setprio(1);
#pragma unroll
      for (int rf = 0; rf < 2; ++rf) {
        short8 ah[4];
#pragma unroll
        for (int kk = 0; kk < 4; ++kk)
          ah[kk] = *(const short8*)(&Hc[(32 + rf * 16 + l15) * 136 + kk * 32 + g4 * 8]);
#pragma unroll
        for (int kk = 0; kk < 4; ++kk)
#pragma unroll
          for (int g = 0; g < 4; ++g)
            acc[rf][g] = __builtin_amdgcn_mfma_f32_16x16x32_bf16(ah[kk], fhh[g][kk], acc[rf][g], 0, 0, 0);
      }
      __builtin_amdgcn_s_setprio(0);
#pragma unroll
      for (int r = 0; r < 2; ++r) {
        const int rr = 2 + r;
#pragma unroll
        for (int q = 0; q < 4; ++q) {
          float ei = __builtin_amdgcn_exp2f(acc[r][0][q]);
          float ef = __builtin_amdgcn_exp2f(acc[r][1][q]);
          float eg = __builtin_amdgcn_exp2f(acc[r][2][q]);
          float eo = __builtin_amdgcn_exp2f(acc[r][3][q]);
          float fv  = __builtin_amdgcn_rcpf(1.0f + ef);
          float rig = __builtin_amdgcn_rcpf((1.0f + ei) * (1.0f + eg));
          float ig  = (eg - 1.0f) * rig;
          float cn  = fv * c[rr][q] + ig;
          float ec  = __builtin_amdgcn_exp2f(cn * TWOLOG2E);
          float rho = __builtin_amdgcn_rcpf((1.0f + eo) * (1.0f + ec));
          float hn  = (ec - 1.0f) * rho;
          bool act = (int)((dgp[rr] >> (8 * q)) & 255u) > t;
          c[rr][q] = act ? cn : c[rr][q];
          u32 word = hpk[rr][q >> 1];
          u16 oldv = (u16)(word >> ((q & 1) * 16));
          u16 nh = act ? f2bf(hn) : oldv;
          hpk[rr][q >> 1] = (q & 1) ? ((word & 0x0000FFFFu) | ((u32)nh << 16))
                                    : ((word & 0xFFFF0000u) | (u32)nh);
          Hn[(rr * 16 + g4 * 4 + q) * 136 + w16 + l15] = nh;
        }
      }
      asm volatile("s_waitcnt lgkmcnt(0)" ::: "memory");
      if (lane == 0) atomicAdd((int*)&hrB[t + 1], 1);
    }

    // ---- publish staged X tiles (DMAs issued ~a full phase ago) ----
    asm volatile("s_waitcnt vmcnt(0)" ::: "memory");
    if (lane == 0) {
      if (t + 2 < maxdegA) atomicAdd((int*)&xrA[t + 2], 1);
      if (t + 2 < maxdegB) atomicAdd((int*)&xrB[t + 2], 1);
    }
  }

  // wait for final h of both recurrences
  spin8(&hrA[maxdegA]);
  spin8(&hrB[maxdegB]);
  const u16* HfA = &Hb[(maxdegA - 1) & 1][0];
  const u16* HfB = &Hb[(maxdegB - 1) & 1][0];

  // out = (h @ W_lin^T) / in_norm + b_lin   (wave w owns out cols 16w..16w+15)
  short8 wl[4];
#pragma unroll
  for (int kk = 0; kk < 4; ++kk)
    wl[kk] = *(const short8*)(wlinb + (size_t)(w16 + l15) * 128 + kk * 32 + g4 * 8);
  f32x4 aA[2] = {}, aB[2] = {};
#pragma unroll
  for (int kk = 0; kk < 4; ++kk)
#pragma unroll
    for (int r = 0; r < 2; ++r) {
      short8 hA = *(const short8*)(&HfA[(r * 16 + l15) * 136 + kk * 32 + g4 * 8]);
      short8 hB = *(const short8*)(&HfB[(32 + r * 16 + l15) * 136 + kk * 32 + g4 * 8]);
      aA[r] = __builtin_amdgcn_mfma_f32_16x16x32_bf16(hA, wl[kk], aA[r], 0, 0, 0);
      aB[r] = __builtin_amdgcn_mfma_f32_16x16x32_bf16(hB, wl[kk], aB[r], 0, 0, 0);
    }
  float blv = blin[w16 + l15];
#pragma unroll
  for (int r = 0; r < 2; ++r)
#pragma unroll
    for (int q = 0; q < 4; ++q) {
      int nl = r * 16 + g4 * 4 + q;
      int gA = gidl[nl];
      int gB = gidl[32 + nl];
      out[(size_t)gA * 128 + w16 + l15] = aA[r][q] / inorm[gA] + blv;
      out[(size_t)gB * 128 + w16 + l15] = aB[r][q] / inorm[gB] + blv;
    }
}

extern "C" void kernel_launch(void* const* d_in, const int* in_sizes, int n_in,
                              void* d_out, int out_size, void* d_ws, size_t ws_size,
                              hipStream_t stream) {
  const float* feat    = (const float*)d_in[0];
  const float* in_norm = (const float*)d_in[1];
  const float* out_nrm = (const float*)d_in[2];
  const float* W_ih    = (const float*)d_in[3];
  const float* W_hh    = (const float*)d_in[4];
  const float* b_ih    = (const float*)d_in[5];
  const float* b_hh    = (const float*)d_in[6];
  const float* W_lin   = (const float*)d_in[7];
  const float* b_lin   = (const float*)d_in[8];
  const int* neighbors = (const int*)d_in[9];
  const int* degrees   = (const int*)d_in[10];
  float* out = (float*)d_out;

  char* ws = (char*)d_ws;
  u16* msg    = (u16*)(ws);                 // 51,200,000 B
  u16* wihb   = (u16*)(ws + 51200000);      //    131,072 B
  u16* whhb   = (u16*)(ws + 51331072);      //    131,072 B
  u16* wlinb  = (u16*)(ws + 51462144);      //     32,768 B
  float* bsum = (float*)(ws + 51494912);    //      2,048 B
  int* perm   = (int*)(ws + 51496960);      //    800,000 B
  int* hist   = (int*)(ws + 52296960);      // 64 ints
  int* basep  = hist + 64;                  // 33 ints
  if (ws_size < 52297600) return;           // need ~52.3 MB scratch

  hipMemsetAsync(hist, 0, 64 * 4, stream);
  k_prep_msg<<<12500, 256, 0, stream>>>(feat, out_nrm, msg);
  k_prep_w<<<578, 256, 0, stream>>>(W_ih, W_hh, W_lin, b_ih, b_hh, wihb, whhb, wlinb, bsum);
  k_hist<<<782, 256, 0, stream>>>(degrees, hist, NN);
  k_scan<<<1, 1, 0, stream>>>(hist, basep);
  k_scatter<<<782, 256, 0, stream>>>(degrees, basep, perm, NN);
  k_main<<<NWG, 512, 0, stream>>>(msg, wihb, whhb, wlinb, bsum, b_lin, in_norm,
                                  neighbors, degrees, perm, out);
}

// Round 13
// 1077.965 us; speedup vs baseline: 1.0697x; 1.0697x over previous
//
#include <hip/hip_runtime.h>

#define NN 200000
#define NB 64
#define NWG (NN / NB)   // 3125

typedef unsigned short u16;
typedef unsigned int u32;
typedef __attribute__((ext_vector_type(8))) short short8;
typedef __attribute__((ext_vector_type(4))) float f32x4;

#define LOG2E 1.4426950408889634f
#define TWOLOG2E 2.8853900817779268f

__device__ __forceinline__ u16 f2bf(float x) {
  u32 u = __float_as_uint(x);
  u += 0x7FFFu + ((u >> 16) & 1u);
  return (u16)(u >> 16);
}

// async global->LDS, 16B per lane; LDS dest = wave-uniform base + lane*16
typedef __attribute__((address_space(3))) unsigned int lds_u32_t;
typedef const __attribute__((address_space(1))) unsigned int glb_u32_t;
__device__ __forceinline__ void gload16(const void* g, void* l) {
  __builtin_amdgcn_global_load_lds((glb_u32_t*)g, (lds_u32_t*)l, 16, 0, 0);
}

// spin until LDS counter reaches 8 (all waves); compiler fence on exit
__device__ __forceinline__ void spin8(const volatile int* p) {
  while (*p < 8) { }
  asm volatile("" ::: "memory");
}

// msg[n][k] = bf16(feat[n][k] / out_norm[n]); 16 threads per row, 8 elems each
__global__ void k_prep_msg(const float* __restrict__ feat, const float* __restrict__ onorm,
                           u16* __restrict__ msg) {
  int i = blockIdx.x * 256 + threadIdx.x;   // 3,200,000 total, exact
  int row = i >> 4, c8 = (i & 15) * 8;
  const float4 a = *(const float4*)(feat + (size_t)row * 128 + c8);
  const float4 b = *(const float4*)(feat + (size_t)row * 128 + c8 + 4);
  float s = 1.0f / onorm[row];
  short8 v = { (short)f2bf(a.x * s), (short)f2bf(a.y * s), (short)f2bf(a.z * s), (short)f2bf(a.w * s),
               (short)f2bf(b.x * s), (short)f2bf(b.y * s), (short)f2bf(b.z * s), (short)f2bf(b.w * s) };
  *(short8*)(msg + (size_t)row * 128 + c8) = v;
}

// Weights with the gate nonlinearity scale FOLDED IN:
//  gates i,f,o: x * -log2(e)  (sigmoid via exp2);  gate g: x * 2*log2(e)
__global__ void k_prep_w(const float* __restrict__ Wih, const float* __restrict__ Whh,
                         const float* __restrict__ Wlin, const float* __restrict__ bih,
                         const float* __restrict__ bhh, u16* __restrict__ wihb,
                         u16* __restrict__ whhb, u16* __restrict__ wlinb,
                         float* __restrict__ bsum) {
  int i = blockIdx.x * 256 + threadIdx.x;   // 147,968 total, exact
  if (i < 65536) {
    int gate = i >> 14;
    float s = (gate == 2) ? TWOLOG2E : -LOG2E;
    wihb[i] = f2bf(Wih[i] * s);
  } else if (i < 131072) {
    int j = i - 65536;
    int gate = j >> 14;
    float s = (gate == 2) ? TWOLOG2E : -LOG2E;
    whhb[j] = f2bf(Whh[j] * s);
  } else if (i < 147456) {
    wlinb[i - 131072] = f2bf(Wlin[i - 131072]);
  } else {
    int j = i - 147456;   // 0..511
    float s = ((j >> 7) == 2) ? TWOLOG2E : -LOG2E;
    bsum[j] = (bih[j] + bhh[j]) * s;
  }
}

__global__ void k_hist(const int* __restrict__ degs, int* __restrict__ hist, int n) {
  __shared__ int lh[33];
  if (threadIdx.x < 33) lh[threadIdx.x] = 0;
  __syncthreads();
  int i = blockIdx.x * 256 + threadIdx.x;
  if (i < n) atomicAdd(&lh[degs[i]], 1);
  __syncthreads();
  if (threadIdx.x < 33 && lh[threadIdx.x]) atomicAdd(&hist[threadIdx.x], lh[threadIdx.x]);
}

__global__ void k_scan(const int* __restrict__ hist, int* __restrict__ basep) {
  if (threadIdx.x == 0 && blockIdx.x == 0) {
    int a = 0;
    for (int d = 32; d >= 1; --d) { basep[d] = a; a += hist[d]; }
    basep[0] = a;
  }
}

__global__ void k_scatter(const int* __restrict__ degs, int* __restrict__ basep,
                          int* __restrict__ perm, int n) {
  __shared__ int lh[33], lbase[33], lc[33];
  int t = threadIdx.x;
  if (t < 33) { lh[t] = 0; lc[t] = 0; }
  __syncthreads();
  int i = blockIdx.x * 256 + t;
  int d = (i < n) ? degs[i] : 0;
  if (i < n) atomicAdd(&lh[d], 1);
  __syncthreads();
  if (t < 33 && lh[t]) lbase[t] = atomicAdd(&basep[t], lh[t]);
  __syncthreads();
  if (i < n) { int r = atomicAdd(&lc[d], 1); perm[lbase[d] + r] = i; }
}

// R11 base (best: 1020us) + finer release granularity:
//  hr0[t] = all waves committed rows 0-31 of h(t-1)  (published mid-body,
//           right after pass0's commit + lgkm drain)
//  hr1[t] = rows 32-63 committed                      (published end-of-body)
//  xr[t]  = X(t) staged (vm drain decoupled from the h-chain publishes)
// pass0-H gates on hr0 only; pass1-H on hr1; DMA slot reuse on hr1 (all
// X(t-1) readers done). Row-disjoint halves keep the skew proof intact.
__global__ __launch_bounds__(512, 2) void k_main(
    const u16* __restrict__ msg, const u16* __restrict__ wihb,
    const u16* __restrict__ whhb, const u16* __restrict__ wlinb,
    const float* __restrict__ bsum, const float* __restrict__ blin,
    const float* __restrict__ inorm, const int* __restrict__ nbrs,
    const int* __restrict__ degs, const int* __restrict__ perm,
    float* __restrict__ out) {
  __shared__ alignas(16) u16 Xb[3][64 * 128];   // X ring (DMA dest, swizzled src)
  __shared__ alignas(16) u16 Hb[2][64 * 136];   // h double buffer, padded
  __shared__ int gidl[64];
  __shared__ int fl[144];   // hr0=fl+0, hr1=fl+36, xr=fl+72 (36 each)

  const int tid = threadIdx.x;
  const int w = tid >> 6;
  const int lane = tid & 63;
  const int l15 = lane & 15;
  const int g4 = lane >> 4;
  const int w16 = w * 16;
  const int gr = tid >> 4;                        // gather rows gr and gr+32
  const int xc8 = (((tid & 15) ^ (gr & 15)) * 8); // swizzled source chunk (u16)
  const int wbase = w * 512;                      // wave's DMA dest base (u16)
  const int base = blockIdx.x * NB;
  volatile int* hr0 = fl;        // rows 0-31 of h(t-1) ready
  volatile int* hr1 = fl + 36;   // rows 32-63 ready
  volatile int* xr  = fl + 72;   // X(t) staged

  // ---- phase 1: gidl, flags, zero Hb[1] (h(-1)) ----
  if (tid < NB) gidl[tid] = perm[base + tid];
  if (tid < 144) fl[tid] = 0;
  if (tid == 0) { fl[0] = 8; fl[36] = 8; }   // hr0[0], hr1[0] preset
  {
    u32* hz = (u32*)Hb[1];
#pragma unroll
    for (int s = 0; s < 8; ++s) hz[tid + s * 512] = 0;
    if (tid < 256) hz[tid + 4096] = 0;
  }
  __syncthreads();

  // ---- phase 2: per-wave loads + stage X(0), X(1) ----
  const int gid0 = gidl[gr], gid1 = gidl[gr + 32];
  const int* nb0 = nbrs + (size_t)gid0 * 32;
  const int* nb1 = nbrs + (size_t)gid1 * 32;

  gload16(msg + (size_t)nb0[0] * 128 + xc8, &Xb[0][wbase]);
  gload16(msg + (size_t)nb1[0] * 128 + xc8, &Xb[0][4096 + wbase]);
  gload16(msg + (size_t)nb0[1] * 128 + xc8, &Xb[1][wbase]);   // row 1 always readable;
  gload16(msg + (size_t)nb1[1] * 128 + xc8, &Xb[1][4096 + wbase]); // unused if deg<2
  int ni0 = nb0[2], ni1 = nb1[2];   // indices for the DMA at t=0 (stages X(2))

  short8 fih[4][4], fhh[4][4];
#pragma unroll
  for (int g = 0; g < 4; ++g)
#pragma unroll
    for (int kk = 0; kk < 4; ++kk) {
      size_t o = (size_t)(g * 128 + w16 + l15) * 128 + kk * 32 + g4 * 8;
      fih[g][kk] = *(const short8*)(wihb + o);
      fhh[g][kk] = *(const short8*)(whhb + o);
    }
  float bias[4];
#pragma unroll
  for (int g = 0; g < 4; ++g) bias[g] = bsum[g * 128 + w16 + l15];

  u32 dgp[4];
#pragma unroll
  for (int r = 0; r < 4; ++r) {
    u32 p = 0;
#pragma unroll
    for (int q = 0; q < 4; ++q) p |= ((u32)degs[gidl[r * 16 + g4 * 4 + q]]) << (8 * q);
    dgp[r] = p;
  }
  const int maxdeg = degs[gidl[0]];   // sorted descending -> WG max (wave-uniform)

  int xsw[4];
#pragma unroll
  for (int kk = 0; kk < 4; ++kk) xsw[kk] = ((kk * 4 + g4) ^ l15) * 8;

  float c[4][4] = {};
  u32 hpk[4][2] = {};

  asm volatile("s_waitcnt vmcnt(0)" ::: "memory");
  if (lane == 0) { atomicAdd((int*)&xr[0], 1); atomicAdd((int*)&xr[1], 1); }

  for (int t = 0; t < maxdeg; ++t) {
    const u16* Xc = &Xb[t % 3][0];
    const u16* Hc = &Hb[(t + 1) & 1][0];   // h(t-1)
    u16* Hn = &Hb[t & 1][0];               // h(t) target

    // ---- pass 0, X-part: gated only on xr[t] (set at end of t-2) ----
    spin8(&xr[t]);
    f32x4 acc[2][4];
#pragma unroll
    for (int r = 0; r < 2; ++r)
#pragma unroll
      for (int g = 0; g < 4; ++g) acc[r][g] = (f32x4){bias[g], bias[g], bias[g], bias[g]};
    __builtin_amdgcn_s_setprio(1);
#pragma unroll
    for (int rf = 0; rf < 2; ++rf) {
      short8 ax[4];
#pragma unroll
      for (int kk = 0; kk < 4; ++kk)
        ax[kk] = *(const short8*)(&Xc[(rf * 16 + l15) * 128 + xsw[kk]]);
#pragma unroll
      for (int kk = 0; kk < 4; ++kk)
#pragma unroll
        for (int g = 0; g < 4; ++g)
          acc[rf][g] = __builtin_amdgcn_mfma_f32_16x16x32_bf16(ax[kk], fih[g][kk], acc[rf][g], 0, 0, 0);
    }
    __builtin_amdgcn_s_setprio(0);

    // ---- pass 0, H-part: needs only rows 0-31 of h(t-1) ----
    spin8(&hr0[t]);
    __builtin_amdgcn_s_setprio(1);
#pragma unroll
    for (int rf = 0; rf < 2; ++rf) {
      short8 ah[4];
#pragma unroll
      for (int kk = 0; kk < 4; ++kk)
        ah[kk] = *(const short8*)(&Hc[(rf * 16 + l15) * 136 + kk * 32 + g4 * 8]);
#pragma unroll
      for (int kk = 0; kk < 4; ++kk)
#pragma unroll
        for (int g = 0; g < 4; ++g)
          acc[rf][g] = __builtin_amdgcn_mfma_f32_16x16x32_bf16(ah[kk], fhh[g][kk], acc[rf][g], 0, 0, 0);
    }
    __builtin_amdgcn_s_setprio(0);
#pragma unroll
    for (int r = 0; r < 2; ++r)
#pragma unroll
      for (int q = 0; q < 4; ++q) {
        float ei = __builtin_amdgcn_exp2f(acc[r][0][q]);
        float ef = __builtin_amdgcn_exp2f(acc[r][1][q]);
        float eg = __builtin_amdgcn_exp2f(acc[r][2][q]);
        float eo = __builtin_amdgcn_exp2f(acc[r][3][q]);
        float fv  = __builtin_amdgcn_rcpf(1.0f + ef);
        float rig = __builtin_amdgcn_rcpf((1.0f + ei) * (1.0f + eg));
        float ig  = (eg - 1.0f) * rig;
        float cn  = fv * c[r][q] + ig;
        float ec  = __builtin_amdgcn_exp2f(cn * TWOLOG2E);
        float rho = __builtin_amdgcn_rcpf((1.0f + eo) * (1.0f + ec));
        float hn  = (ec - 1.0f) * rho;
        bool act = (int)((dgp[r] >> (8 * q)) & 255u) > t;
        c[r][q] = act ? cn : c[r][q];
        u32 word = hpk[r][q >> 1];
        u16 oldv = (u16)(word >> ((q & 1) * 16));
        u16 nh = act ? f2bf(hn) : oldv;
        hpk[r][q >> 1] = (q & 1) ? ((word & 0x0000FFFFu) | ((u32)nh << 16))
                                 : ((word & 0xFFFF0000u) | (u32)nh);
        Hn[(r * 16 + g4 * 4 + q) * 136 + w16 + l15] = nh;
      }
    // publish rows 0-31 of h(t) EARLY (only lgkm needs draining)
    asm volatile("s_waitcnt lgkmcnt(0)" ::: "memory");
    if (lane == 0) atomicAdd((int*)&hr0[t + 1], 1);

    // ---- pass 1: needs rows 32-63 of h(t-1); also gates DMA slot reuse ----
    spin8(&hr1[t]);
    // ring slot (t+2)%3 free: hr1[t]==8 => all waves' X(t-1) reads done
    if (t + 2 < maxdeg) {
      gload16(msg + (size_t)ni0 * 128 + xc8, &Xb[(t + 2) % 3][wbase]);
      gload16(msg + (size_t)ni1 * 128 + xc8, &Xb[(t + 2) % 3][4096 + wbase]);
    }
    { int nt = (t + 3) <= 31 ? (t + 3) : 31; ni0 = nb0[nt]; ni1 = nb1[nt]; }

#pragma unroll
    for (int r = 0; r < 2; ++r)
#pragma unroll
      for (int g = 0; g < 4; ++g) acc[r][g] = (f32x4){bias[g], bias[g], bias[g], bias[g]};
    __builtin_amdgcn_s_setprio(1);
#pragma unroll
    for (int rf = 0; rf < 2; ++rf) {
      short8 ax[4];
#pragma unroll
      for (int kk = 0; kk < 4; ++kk)
        ax[kk] = *(const short8*)(&Xc[(32 + rf * 16 + l15) * 128 + xsw[kk]]);
#pragma unroll
      for (int kk = 0; kk < 4; ++kk)
#pragma unroll
        for (int g = 0; g < 4; ++g)
          acc[rf][g] = __builtin_amdgcn_mfma_f32_16x16x32_bf16(ax[kk], fih[g][kk], acc[rf][g], 0, 0, 0);
    }
#pragma unroll
    for (int rf = 0; rf < 2; ++rf) {
      short8 ah[4];
#pragma unroll
      for (int kk = 0; kk < 4; ++kk)
        ah[kk] = *(const short8*)(&Hc[(32 + rf * 16 + l15) * 136 + kk * 32 + g4 * 8]);
#pragma unroll
      for (int kk = 0; kk < 4; ++kk)
#pragma unroll
        for (int g = 0; g < 4; ++g)
          acc[rf][g] = __builtin_amdgcn_mfma_f32_16x16x32_bf16(ah[kk], fhh[g][kk], acc[rf][g], 0, 0, 0);
    }
    __builtin_amdgcn_s_setprio(0);
#pragma unroll
    for (int r = 0; r < 2; ++r) {
      const int rr = 2 + r;
#pragma unroll
      for (int q = 0; q < 4; ++q) {
        float ei = __builtin_amdgcn_exp2f(acc[r][0][q]);
        float ef = __builtin_amdgcn_exp2f(acc[r][1][q]);
        float eg = __builtin_amdgcn_exp2f(acc[r][2][q]);
        float eo = __builtin_amdgcn_exp2f(acc[r][3][q]);
        float fv  = __builtin_amdgcn_rcpf(1.0f + ef);
        float rig = __builtin_amdgcn_rcpf((1.0f + ei) * (1.0f + eg));
        float ig  = (eg - 1.0f) * rig;
        float cn  = fv * c[rr][q] + ig;
        float ec  = __builtin_amdgcn_exp2f(cn * TWOLOG2E);
        float rho = __builtin_amdgcn_rcpf((1.0f + eo) * (1.0f + ec));
        float hn  = (ec - 1.0f) * rho;
        bool act = (int)((dgp[rr] >> (8 * q)) & 255u) > t;
        c[rr][q] = act ? cn : c[rr][q];
        u32 word = hpk[rr][q >> 1];
        u16 oldv = (u16)(word >> ((q & 1) * 16));
        u16 nh = act ? f2bf(hn) : oldv;
        hpk[rr][q >> 1] = (q & 1) ? ((word & 0x0000FFFFu) | ((u32)nh << 16))
                                  : ((word & 0xFFFF0000u) | (u32)nh);
        Hn[(rr * 16 + g4 * 4 + q) * 136 + w16 + l15] = nh;
      }
    }
    // publish rows 32-63 (lgkm), then the staged X tile (vm) — decoupled
    asm volatile("s_waitcnt lgkmcnt(0)" ::: "memory");
    if (lane == 0) atomicAdd((int*)&hr1[t + 1], 1);
    asm volatile("s_waitcnt vmcnt(0)" ::: "memory");
    if (lane == 0) atomicAdd((int*)&xr[t + 2], 1);
  }

  // hr1[maxdeg]==8 implies hr0[maxdeg]==8 (each wave publishes hr0 first)
  spin8(&hr1[maxdeg]);
  const u16* Hf = &Hb[(maxdeg - 1) & 1][0];

  // out = (h @ W_lin^T) / in_norm + b_lin   (wave w owns out cols 16w..16w+15)
  short8 wl[4];
#pragma unroll
  for (int kk = 0; kk < 4; ++kk)
    wl[kk] = *(const short8*)(wlinb + (size_t)(w16 + l15) * 128 + kk * 32 + g4 * 8);
  f32x4 a2[4] = {};
#pragma unroll
  for (int kk = 0; kk < 4; ++kk)
#pragma unroll
    for (int r = 0; r < 4; ++r) {
      short8 ah = *(const short8*)(&Hf[(r * 16 + l15) * 136 + kk * 32 + g4 * 8]);
      a2[r] = __builtin_amdgcn_mfma_f32_16x16x32_bf16(ah, wl[kk], a2[r], 0, 0, 0);
    }
  float blv = blin[w16 + l15];
#pragma unroll
  for (int r = 0; r < 4; ++r)
#pragma unroll
    for (int q = 0; q < 4; ++q) {
      int nl = r * 16 + g4 * 4 + q;
      int g = gidl[nl];
      out[(size_t)g * 128 + w16 + l15] = a2[r][q] / inorm[g] + blv;
    }
}

extern "C" void kernel_launch(void* const* d_in, const int* in_sizes, int n_in,
                              void* d_out, int out_size, void* d_ws, size_t ws_size,
                              hipStream_t stream) {
  const float* feat    = (const float*)d_in[0];
  const float* in_norm = (const float*)d_in[1];
  const float* out_nrm = (const float*)d_in[2];
  const float* W_ih    = (const float*)d_in[3];
  const float* W_hh    = (const float*)d_in[4];
  const float* b_ih    = (const float*)d_in[5];
  const float* b_hh    = (const float*)d_in[6];
  const float* W_lin   = (const float*)d_in[7];
  const float* b_lin   = (const float*)d_in[8];
  const int* neighbors = (const int*)d_in[9];
  const int* degrees   = (const int*)d_in[10];
  float* out = (float*)d_out;

  char* ws = (char*)d_ws;
  u16* msg    = (u16*)(ws);                 // 51,200,000 B
  u16* wihb   = (u16*)(ws + 51200000);      //    131,072 B
  u16* whhb   = (u16*)(ws + 51331072);      //    131,072 B
  u16* wlinb  = (u16*)(ws + 51462144);      //     32,768 B
  float* bsum = (float*)(ws + 51494912);    //      2,048 B
  int* perm   = (int*)(ws + 51496960);      //    800,000 B
  int* hist   = (int*)(ws + 52296960);      // 64 ints
  int* basep  = hist + 64;                  // 33 ints
  if (ws_size < 52297600) return;           // need ~52.3 MB scratch

  hipMemsetAsync(hist, 0, 64 * 4, stream);
  k_prep_msg<<<12500, 256, 0, stream>>>(feat, out_nrm, msg);
  k_prep_w<<<578, 256, 0, stream>>>(W_ih, W_hh, W_lin, b_ih, b_hh, wihb, whhb, wlinb, bsum);
  k_hist<<<782, 256, 0, stream>>>(degrees, hist, NN);
  k_scan<<<1, 1, 0, stream>>>(hist, basep);
  k_scatter<<<782, 256, 0, stream>>>(degrees, basep, perm, NN);
  k_main<<<NWG, 512, 0, stream>>>(msg, wihb, whhb, wlinb, bsum, b_lin, in_norm,
                                  neighbors, degrees, perm, out);
}

// Round 14
// 1019.105 us; speedup vs baseline: 1.1315x; 1.0578x over previous
//
#include <hip/hip_runtime.h>

#define NN 200000
#define NB 64
#define NWG (NN / NB)   // 3125

typedef unsigned short u16;
typedef unsigned int u32;
typedef __attribute__((ext_vector_type(8))) short short8;
typedef __attribute__((ext_vector_type(4))) float f32x4;

#define LOG2E 1.4426950408889634f
#define TWOLOG2E 2.8853900817779268f

__device__ __forceinline__ u16 f2bf(float x) {
  u32 u = __float_as_uint(x);
  u += 0x7FFFu + ((u >> 16) & 1u);
  return (u16)(u >> 16);
}

// async global->LDS, 16B per lane; LDS dest = wave-uniform base + lane*16
typedef __attribute__((address_space(3))) unsigned int lds_u32_t;
typedef const __attribute__((address_space(1))) unsigned int glb_u32_t;
__device__ __forceinline__ void gload16(const void* g, void* l) {
  __builtin_amdgcn_global_load_lds((glb_u32_t*)g, (lds_u32_t*)l, 16, 0, 0);
}

// spin until LDS counter reaches 8 (all waves); compiler fence on exit
__device__ __forceinline__ void spin8(const volatile int* p) {
  while (*p < 8) { }
  asm volatile("" ::: "memory");
}

// msg[n][k] = bf16(feat[n][k] / out_norm[n]); 16 threads per row, 8 elems each
__global__ void k_prep_msg(const float* __restrict__ feat, const float* __restrict__ onorm,
                           u16* __restrict__ msg) {
  int i = blockIdx.x * 256 + threadIdx.x;   // 3,200,000 total, exact
  int row = i >> 4, c8 = (i & 15) * 8;
  const float4 a = *(const float4*)(feat + (size_t)row * 128 + c8);
  const float4 b = *(const float4*)(feat + (size_t)row * 128 + c8 + 4);
  float s = 1.0f / onorm[row];
  short8 v = { (short)f2bf(a.x * s), (short)f2bf(a.y * s), (short)f2bf(a.z * s), (short)f2bf(a.w * s),
               (short)f2bf(b.x * s), (short)f2bf(b.y * s), (short)f2bf(b.z * s), (short)f2bf(b.w * s) };
  *(short8*)(msg + (size_t)row * 128 + c8) = v;
}

// Weights with the gate nonlinearity scale FOLDED IN:
//  gates i,f,o: x * -log2(e)  (sigmoid via exp2);  gate g: x * 2*log2(e)
__global__ void k_prep_w(const float* __restrict__ Wih, const float* __restrict__ Whh,
                         const float* __restrict__ Wlin, const float* __restrict__ bih,
                         const float* __restrict__ bhh, u16* __restrict__ wihb,
                         u16* __restrict__ whhb, u16* __restrict__ wlinb,
                         float* __restrict__ bsum) {
  int i = blockIdx.x * 256 + threadIdx.x;   // 147,968 total, exact
  if (i < 65536) {
    int gate = i >> 14;
    float s = (gate == 2) ? TWOLOG2E : -LOG2E;
    wihb[i] = f2bf(Wih[i] * s);
  } else if (i < 131072) {
    int j = i - 65536;
    int gate = j >> 14;
    float s = (gate == 2) ? TWOLOG2E : -LOG2E;
    whhb[j] = f2bf(Whh[j] * s);
  } else if (i < 147456) {
    wlinb[i - 131072] = f2bf(Wlin[i - 131072]);
  } else {
    int j = i - 147456;   // 0..511
    float s = ((j >> 7) == 2) ? TWOLOG2E : -LOG2E;
    bsum[j] = (bih[j] + bhh[j]) * s;
  }
}

__global__ void k_hist(const int* __restrict__ degs, int* __restrict__ hist, int n) {
  __shared__ int lh[33];
  if (threadIdx.x < 33) lh[threadIdx.x] = 0;
  __syncthreads();
  int i = blockIdx.x * 256 + threadIdx.x;
  if (i < n) atomicAdd(&lh[degs[i]], 1);
  __syncthreads();
  if (threadIdx.x < 33 && lh[threadIdx.x]) atomicAdd(&hist[threadIdx.x], lh[threadIdx.x]);
}

__global__ void k_scan(const int* __restrict__ hist, int* __restrict__ basep) {
  if (threadIdx.x == 0 && blockIdx.x == 0) {
    int a = 0;
    for (int d = 32; d >= 1; --d) { basep[d] = a; a += hist[d]; }
    basep[0] = a;
  }
}

__global__ void k_scatter(const int* __restrict__ degs, int* __restrict__ basep,
                          int* __restrict__ perm, int n) {
  __shared__ int lh[33], lbase[33], lc[33];
  int t = threadIdx.x;
  if (t < 33) { lh[t] = 0; lc[t] = 0; }
  __syncthreads();
  int i = blockIdx.x * 256 + t;
  int d = (i < n) ? degs[i] : 0;
  if (i < n) atomicAdd(&lh[d], 1);
  __syncthreads();
  if (t < 33 && lh[t]) lbase[t] = atomicAdd(&basep[t], lh[t]);
  __syncthreads();
  if (i < n) { int r = atomicAdd(&lc[d], 1); perm[lbase[d] + r] = i; }
}

// Barrier-free recurrence: per-step block-wide s_barrier replaced by LDS
// flag counters so waves self-stagger. Per step: X-MFMA runs BEFORE the
// cross-wave wait (gated only on xr[t], set at end of step t-2); the hr[t]
// spin (the true h(t-1) dependency) is covered by X-MFMA work; X staged
// 2 steps ahead into a 3-buffer ring. Register envelope = R9 (no spill).
// FINAL: best verified structure (R11, 1020us). R12 (dual-chain) and R13
// (split release flags) both regressed — the remaining gap is the serial
// h-chain round-trip, unhideable at the register-forced 2 waves/SIMD.
__global__ __launch_bounds__(512, 2) void k_main(
    const u16* __restrict__ msg, const u16* __restrict__ wihb,
    const u16* __restrict__ whhb, const u16* __restrict__ wlinb,
    const float* __restrict__ bsum, const float* __restrict__ blin,
    const float* __restrict__ inorm, const int* __restrict__ nbrs,
    const int* __restrict__ degs, const int* __restrict__ perm,
    float* __restrict__ out) {
  __shared__ alignas(16) u16 Xb[3][64 * 128];   // X ring (DMA dest, swizzled src)
  __shared__ alignas(16) u16 Hb[2][64 * 136];   // h double buffer, padded
  __shared__ int gidl[64];
  __shared__ int fl[72];                         // fl[0..33]=hr, fl[36..69]=xr
  // total ~84.5 KB

  const int tid = threadIdx.x;
  const int w = tid >> 6;
  const int lane = tid & 63;
  const int l15 = lane & 15;
  const int g4 = lane >> 4;
  const int w16 = w * 16;
  const int gr = tid >> 4;                        // gather rows gr and gr+32
  const int xc8 = (((tid & 15) ^ (gr & 15)) * 8); // swizzled source chunk (u16)
  const int wbase = w * 512;                      // wave's DMA dest base (u16)
  const int base = blockIdx.x * NB;
  volatile int* hr = fl;        // hr[t] == 8  <=>  h(t-1) published by all waves
  volatile int* xr = fl + 36;   // xr[t] == 8  <=>  X(t) fully staged

  // ---- phase 1: gidl, flags, zero Hb[1] (h(-1)) ----
  if (tid < NB) gidl[tid] = perm[base + tid];
  if (tid < 72) fl[tid] = (tid == 0) ? 8 : 0;   // hr[0] preset (no producer for t=-1)
  {
    u32* hz = (u32*)Hb[1];
#pragma unroll
    for (int s = 0; s < 8; ++s) hz[tid + s * 512] = 0;
    if (tid < 256) hz[tid + 4096] = 0;
  }
  __syncthreads();

  // ---- phase 2: per-wave loads + stage X(0), X(1) ----
  const int gid0 = gidl[gr], gid1 = gidl[gr + 32];
  const int* nb0 = nbrs + (size_t)gid0 * 32;
  const int* nb1 = nbrs + (size_t)gid1 * 32;

  gload16(msg + (size_t)nb0[0] * 128 + xc8, &Xb[0][wbase]);
  gload16(msg + (size_t)nb1[0] * 128 + xc8, &Xb[0][4096 + wbase]);
  gload16(msg + (size_t)nb0[1] * 128 + xc8, &Xb[1][wbase]);   // idx always readable;
  gload16(msg + (size_t)nb1[1] * 128 + xc8, &Xb[1][4096 + wbase]); // unused if deg<2
  int ni0 = nb0[2], ni1 = nb1[2];   // indices for the DMA at t=0 (stages X(2))

  short8 fih[4][4], fhh[4][4];
#pragma unroll
  for (int g = 0; g < 4; ++g)
#pragma unroll
    for (int kk = 0; kk < 4; ++kk) {
      size_t o = (size_t)(g * 128 + w16 + l15) * 128 + kk * 32 + g4 * 8;
      fih[g][kk] = *(const short8*)(wihb + o);
      fhh[g][kk] = *(const short8*)(whhb + o);
    }
  float bias[4];
#pragma unroll
  for (int g = 0; g < 4; ++g) bias[g] = bsum[g * 128 + w16 + l15];

  u32 dgp[4];
#pragma unroll
  for (int r = 0; r < 4; ++r) {
    u32 p = 0;
#pragma unroll
    for (int q = 0; q < 4; ++q) p |= ((u32)degs[gidl[r * 16 + g4 * 4 + q]]) << (8 * q);
    dgp[r] = p;
  }
  const int maxdeg = degs[gidl[0]];   // sorted descending -> WG max (wave-uniform)

  int xsw[4];
#pragma unroll
  for (int kk = 0; kk < 4; ++kk) xsw[kk] = ((kk * 4 + g4) ^ l15) * 8;

  float c[4][4] = {};
  u32 hpk[4][2] = {};

  // publish X(0), X(1) staged (after all prologue vmem drains)
  asm volatile("s_waitcnt vmcnt(0)" ::: "memory");
  if (lane == 0) { atomicAdd((int*)&xr[0], 1); atomicAdd((int*)&xr[1], 1); }

  for (int t = 0; t < maxdeg; ++t) {
    const u16* Xc = &Xb[t % 3][0];
    const u16* Hc = &Hb[(t + 1) & 1][0];   // h(t-1)
    u16* Hn = &Hb[t & 1][0];               // h(t) target

    // ---- pass 0, X-part: only needs xr[t] (set at end of t-2 -> ~free) ----
    spin8(&xr[t]);
    f32x4 acc[2][4];
#pragma unroll
    for (int r = 0; r < 2; ++r)
#pragma unroll
      for (int g = 0; g < 4; ++g) acc[r][g] = (f32x4){bias[g], bias[g], bias[g], bias[g]};
    __builtin_amdgcn_s_setprio(1);
#pragma unroll
    for (int rf = 0; rf < 2; ++rf) {
      short8 ax[4];
#pragma unroll
      for (int kk = 0; kk < 4; ++kk)
        ax[kk] = *(const short8*)(&Xc[(rf * 16 + l15) * 128 + xsw[kk]]);
#pragma unroll
      for (int kk = 0; kk < 4; ++kk)
#pragma unroll
        for (int g = 0; g < 4; ++g)
          acc[rf][g] = __builtin_amdgcn_mfma_f32_16x16x32_bf16(ax[kk], fih[g][kk], acc[rf][g], 0, 0, 0);
    }
    __builtin_amdgcn_s_setprio(0);

    // ---- the true cross-wave dependency: h(t-1) published by all waves ----
    spin8(&hr[t]);

    // stage X(t+2) into ring slot (t+2)%3 — provably free: hr[t]>=8 means all
    // waves finished step t-1, hence all X-reads of X(t-1) (same slot) done
    if (t + 2 < maxdeg) {
      gload16(msg + (size_t)ni0 * 128 + xc8, &Xb[(t + 2) % 3][wbase]);
      gload16(msg + (size_t)ni1 * 128 + xc8, &Xb[(t + 2) % 3][4096 + wbase]);
    }
    { int nt = (t + 3) <= 31 ? (t + 3) : 31; ni0 = nb0[nt]; ni1 = nb1[nt]; }

    // ---- pass 0, H-part + epilogue + commit (rows 0-31) ----
    __builtin_amdgcn_s_setprio(1);
#pragma unroll
    for (int rf = 0; rf < 2; ++rf) {
      short8 ah[4];
#pragma unroll
      for (int kk = 0; kk < 4; ++kk)
        ah[kk] = *(const short8*)(&Hc[(rf * 16 + l15) * 136 + kk * 32 + g4 * 8]);
#pragma unroll
      for (int kk = 0; kk < 4; ++kk)
#pragma unroll
        for (int g = 0; g < 4; ++g)
          acc[rf][g] = __builtin_amdgcn_mfma_f32_16x16x32_bf16(ah[kk], fhh[g][kk], acc[rf][g], 0, 0, 0);
    }
    __builtin_amdgcn_s_setprio(0);
#pragma unroll
    for (int r = 0; r < 2; ++r)
#pragma unroll
      for (int q = 0; q < 4; ++q) {
        float ei = __builtin_amdgcn_exp2f(acc[r][0][q]);
        float ef = __builtin_amdgcn_exp2f(acc[r][1][q]);
        float eg = __builtin_amdgcn_exp2f(acc[r][2][q]);
        float eo = __builtin_amdgcn_exp2f(acc[r][3][q]);
        float fv  = __builtin_amdgcn_rcpf(1.0f + ef);
        float rig = __builtin_amdgcn_rcpf((1.0f + ei) * (1.0f + eg));
        float ig  = (eg - 1.0f) * rig;
        float cn  = fv * c[r][q] + ig;
        float ec  = __builtin_amdgcn_exp2f(cn * TWOLOG2E);
        float rho = __builtin_amdgcn_rcpf((1.0f + eo) * (1.0f + ec));
        float hn  = (ec - 1.0f) * rho;
        bool act = (int)((dgp[r] >> (8 * q)) & 255u) > t;
        c[r][q] = act ? cn : c[r][q];
        u32 word = hpk[r][q >> 1];
        u16 oldv = (u16)(word >> ((q & 1) * 16));
        u16 nh = act ? f2bf(hn) : oldv;
        hpk[r][q >> 1] = (q & 1) ? ((word & 0x0000FFFFu) | ((u32)nh << 16))
                                 : ((word & 0xFFFF0000u) | (u32)nh);
        Hn[(r * 16 + g4 * 4 + q) * 136 + w16 + l15] = nh;
      }

    // ---- pass 1 (rows 32-63): X-part + H-part + epilogue + commit ----
#pragma unroll
    for (int r = 0; r < 2; ++r)
#pragma unroll
      for (int g = 0; g < 4; ++g) acc[r][g] = (f32x4){bias[g], bias[g], bias[g], bias[g]};
    __builtin_amdgcn_s_setprio(1);
#pragma unroll
    for (int rf = 0; rf < 2; ++rf) {
      short8 ax[4];
#pragma unroll
      for (int kk = 0; kk < 4; ++kk)
        ax[kk] = *(const short8*)(&Xc[(32 + rf * 16 + l15) * 128 + xsw[kk]]);
#pragma unroll
      for (int kk = 0; kk < 4; ++kk)
#pragma unroll
        for (int g = 0; g < 4; ++g)
          acc[rf][g] = __builtin_amdgcn_mfma_f32_16x16x32_bf16(ax[kk], fih[g][kk], acc[rf][g], 0, 0, 0);
    }
#pragma unroll
    for (int rf = 0; rf < 2; ++rf) {
      short8 ah[4];
#pragma unroll
      for (int kk = 0; kk < 4; ++kk)
        ah[kk] = *(const short8*)(&Hc[(32 + rf * 16 + l15) * 136 + kk * 32 + g4 * 8]);
#pragma unroll
      for (int kk = 0; kk < 4; ++kk)
#pragma unroll
        for (int g = 0; g < 4; ++g)
          acc[rf][g] = __builtin_amdgcn_mfma_f32_16x16x32_bf16(ah[kk], fhh[g][kk], acc[rf][g], 0, 0, 0);
    }
    __builtin_amdgcn_s_setprio(0);
#pragma unroll
    for (int r = 0; r < 2; ++r) {
      const int rr = 2 + r;
#pragma unroll
      for (int q = 0; q < 4; ++q) {
        float ei = __builtin_amdgcn_exp2f(acc[r][0][q]);
        float ef = __builtin_amdgcn_exp2f(acc[r][1][q]);
        float eg = __builtin_amdgcn_exp2f(acc[r][2][q]);
        float eo = __builtin_amdgcn_exp2f(acc[r][3][q]);
        float fv  = __builtin_amdgcn_rcpf(1.0f + ef);
        float rig = __builtin_amdgcn_rcpf((1.0f + ei) * (1.0f + eg));
        float ig  = (eg - 1.0f) * rig;
        float cn  = fv * c[rr][q] + ig;
        float ec  = __builtin_amdgcn_exp2f(cn * TWOLOG2E);
        float rho = __builtin_amdgcn_rcpf((1.0f + eo) * (1.0f + ec));
        float hn  = (ec - 1.0f) * rho;
        bool act = (int)((dgp[rr] >> (8 * q)) & 255u) > t;
        c[rr][q] = act ? cn : c[rr][q];
        u32 word = hpk[rr][q >> 1];
        u16 oldv = (u16)(word >> ((q & 1) * 16));
        u16 nh = act ? f2bf(hn) : oldv;
        hpk[rr][q >> 1] = (q & 1) ? ((word & 0x0000FFFFu) | ((u32)nh << 16))
                                  : ((word & 0xFFFF0000u) | (u32)nh);
        Hn[((rr) * 16 + g4 * 4 + q) * 136 + w16 + l15] = nh;
      }
    }

    // ---- publish: h(t) committed (lgkm) and X(t+2) landed (vm) ----
    asm volatile("s_waitcnt vmcnt(0) lgkmcnt(0)" ::: "memory");
    if (lane == 0) {
      atomicAdd((int*)&hr[t + 1], 1);
      atomicAdd((int*)&xr[t + 2], 1);
    }
  }

  // wait for the final h from all waves
  spin8(&hr[maxdeg]);
  const u16* Hf = &Hb[(maxdeg - 1) & 1][0];

  // out = (h @ W_lin^T) / in_norm + b_lin   (wave w owns out cols 16w..16w+15)
  short8 wl[4];
#pragma unroll
  for (int kk = 0; kk < 4; ++kk)
    wl[kk] = *(const short8*)(wlinb + (size_t)(w16 + l15) * 128 + kk * 32 + g4 * 8);
  f32x4 a2[4] = {};
#pragma unroll
  for (int kk = 0; kk < 4; ++kk)
#pragma unroll
    for (int r = 0; r < 4; ++r) {
      short8 ah = *(const short8*)(&Hf[(r * 16 + l15) * 136 + kk * 32 + g4 * 8]);
      a2[r] = __builtin_amdgcn_mfma_f32_16x16x32_bf16(ah, wl[kk], a2[r], 0, 0, 0);
    }
  float blv = blin[w16 + l15];
#pragma unroll
  for (int r = 0; r < 4; ++r)
#pragma unroll
    for (int q = 0; q < 4; ++q) {
      int nl = r * 16 + g4 * 4 + q;
      int g = gidl[nl];
      out[(size_t)g * 128 + w16 + l15] = a2[r][q] / inorm[g] + blv;
    }
}

extern "C" void kernel_launch(void* const* d_in, const int* in_sizes, int n_in,
                              void* d_out, int out_size, void* d_ws, size_t ws_size,
                              hipStream_t stream) {
  const float* feat    = (const float*)d_in[0];
  const float* in_norm = (const float*)d_in[1];
  const float* out_nrm = (const float*)d_in[2];
  const float* W_ih    = (const float*)d_in[3];
  const float* W_hh    = (const float*)d_in[4];
  const float* b_ih    = (const float*)d_in[5];
  const float* b_hh    = (const float*)d_in[6];
  const float* W_lin   = (const float*)d_in[7];
  const float* b_lin   = (const float*)d_in[8];
  const int* neighbors = (const int*)d_in[9];
  const int* degrees   = (const int*)d_in[10];
  float* out = (float*)d_out;

  char* ws = (char*)d_ws;
  u16* msg    = (u16*)(ws);                 // 51,200,000 B
  u16* wihb   = (u16*)(ws + 51200000);      //    131,072 B
  u16* whhb   = (u16*)(ws + 51331072);      //    131,072 B
  u16* wlinb  = (u16*)(ws + 51462144);      //     32,768 B
  float* bsum = (float*)(ws + 51494912);    //      2,048 B
  int* perm   = (int*)(ws + 51496960);      //    800,000 B
  int* hist   = (int*)(ws + 52296960);      // 64 ints
  int* basep  = hist + 64;                  // 33 ints
  if (ws_size < 52297600) return;           // need ~52.3 MB scratch

  hipMemsetAsync(hist, 0, 64 * 4, stream);
  k_prep_msg<<<12500, 256, 0, stream>>>(feat, out_nrm, msg);
  k_prep_w<<<578, 256, 0, stream>>>(W_ih, W_hh, W_lin, b_ih, b_hh, wihb, whhb, wlinb, bsum);
  k_hist<<<782, 256, 0, stream>>>(degrees, hist, NN);
  k_scan<<<1, 1, 0, stream>>>(hist, basep);
  k_scatter<<<782, 256, 0, stream>>>(degrees, basep, perm, NN);
  k_main<<<NWG, 512, 0, stream>>>(msg, wihb, whhb, wlinb, bsum, b_lin, in_norm,
                                  neighbors, degrees, perm, out);
}